// Round 9
// baseline (176.482 us; speedup 1.0000x reference)
//
#include <hip/hip_runtime.h>
#include <hip/hip_bf16.h>
#include <stdint.h>

#define NN 2048
#define DD 256
#define LL 4
#define DIN 128
#define DOUT 64
#define EE 65536
#define BM 4          // rows per block; NN/BM = 512 blocks (2 per CU)

// ---------------------------------------------------------------------------
// Established in rounds 0-8:
// * Float tensors are f32 in AND out (rounds 5-8 PASS via f32 path; round-1
//   NaN is the f32-read-as-bf16 signature).
// * Attention contributes EXACTLY zero: reference multiplies logits by -1e6
//   for cross-graph pairs -> softmax max ~ +1e5 (cross-graph), in-graph
//   entries underflow to exp(-O(1e5)) == 0.0 in f32, and cross-graph winners
//   are zeroed by the post-softmax mask. Verified empirically in rounds 2/3
//   (full attention, two pipelines, bit-identical outputs).
// * Surviving computation (row-independent after deg):
//     h0 = x@Win + b_in + z[clip(deg,0,63)]
//     per layer l: xp = h + bo[l]; h = LN2(xp)@Wff[l] + bff[l] + xp
//     out = h@Wout + b_out
// * R7: 256 thr/block @1 blk/CU -> 1 wave/SIMD, latency-bound (VALU 14%).
// * R8: 1024 thr/block, 256 blocks -> occ 41%, VALU 22%, 56 us. Still
//   barrier/latency bound at 1 block/CU. This round: BM=4 (512 blocks,
//   2 blocks/CU), single-pass LN (3 barriers/layer instead of 6).
// ---------------------------------------------------------------------------

__global__ __launch_bounds__(256) void k_deg(const int* __restrict__ ei, int* __restrict__ deg) {
    int t = blockIdx.x * 256 + threadIdx.x;
    if (t < EE) {
        unsigned v = (unsigned)ei[t];
        if (v < NN) atomicAdd(&deg[v], 1);
    }
}

__global__ __launch_bounds__(256) void k_fill(float* __restrict__ p, int n, float v) {
    int t = blockIdx.x * 256 + threadIdx.x;
    if (t < n) p[t] = v;
}

__global__ __launch_bounds__(1024) void k_mega(
        const float* __restrict__ x, const int* __restrict__ deg,
        const float* __restrict__ Win, const float* __restrict__ bin, const float* __restrict__ z,
        const float* __restrict__ bo, const float* __restrict__ lnw, const float* __restrict__ lnb,
        const float* __restrict__ Wff, const float* __restrict__ bff,
        const float* __restrict__ Wout, const float* __restrict__ bout,
        float* __restrict__ out) {
    int n0 = blockIdx.x * BM;
    int tid = threadIdx.x;
    int c = tid >> 8;        // k-chunk AND owned row, 0..3
    int d = tid & 255;       // column 0..255
    int lane = tid & 63;
    int wv = d >> 6;         // wave-within-c-group 0..3

    __shared__ float sh[BM][DD];        // current h rows        4 KB
    __shared__ float sxp[BM][DD];       // xp rows               4 KB
    __shared__ float shnT[DD][BM];      // LN out, transposed    4 KB
    __shared__ float part[4][BM][DD];   // K-split partials     16 KB
    __shared__ float xsT[DIN][BM];      // x rows, transposed    2 KB
    __shared__ float red[BM][4][2];     // LN sum/sumsq partials

    // ---- stage x (transposed) ----
    if (tid < BM * DIN) {
        int r = tid >> 7, k = tid & 127;
        xsT[k][r] = x[(size_t)(n0 + r) * DIN + k];
    }
    __syncthreads();

    // ---- h0 partials: k in [c*32, c*32+32) ----
    {
        float acc0 = 0.f, acc1 = 0.f, acc2 = 0.f, acc3 = 0.f;
        const float* W = Win + d;
#pragma unroll 8
        for (int k = c * 32; k < c * 32 + 32; k++) {
            float w = W[(size_t)k * DD];
            float4 a = *(const float4*)&xsT[k][0];
            acc0 += a.x * w; acc1 += a.y * w; acc2 += a.z * w; acc3 += a.w * w;
        }
        part[c][0][d] = acc0; part[c][1][d] = acc1;
        part[c][2][d] = acc2; part[c][3][d] = acc3;
    }
    __syncthreads();
    // combine h0: c-group owns row r = c
    {
        int dg = deg[n0 + c];
        dg = dg < 0 ? 0 : (dg > 63 ? 63 : dg);
        sh[c][d] = part[0][c][d] + part[1][c][d] + part[2][c][d] + part[3][c][d]
                 + bin[d] + z[(size_t)dg * DD + d];
    }
    // no barrier: sh[c][d] read next only by its writer (xp stage below)

    // ---- 4 fused layers ----
    for (int l = 0; l < LL; l++) {
        float bo_d = bo[(size_t)l * DD + d];
        float lw = lnw[(size_t)l * DD + d];
        float lb = lnb[(size_t)l * DD + d];

        // xp + single-pass LN stats for own row c
        float xpv = sh[c][d] + bo_d;
        sxp[c][d] = xpv;
        float s = xpv, q = xpv * xpv;
#pragma unroll
        for (int o = 32; o; o >>= 1) {
            s += __shfl_down(s, o, 64);
            q += __shfl_down(q, o, 64);
        }
        if (lane == 0) { red[c][wv][0] = s; red[c][wv][1] = q; }
        __syncthreads();                                   // B1
        float sum = red[c][0][0] + red[c][1][0] + red[c][2][0] + red[c][3][0];
        float sq  = red[c][0][1] + red[c][1][1] + red[c][2][1] + red[c][3][1];
        float mu = sum * (1.0f / 256.0f);
        float var = sq * (1.0f / 256.0f) - mu * mu;
        float inv = 1.0f / sqrtf(var + 1e-5f);
        shnT[d][c] = (xpv - mu) * inv * lw + lb;
        __syncthreads();                                   // B2

        // FF partials: k in [c*64, c*64+64)
        {
            float acc0 = 0.f, acc1 = 0.f, acc2 = 0.f, acc3 = 0.f;
            const float* W = Wff + (size_t)l * DD * DD + d;
#pragma unroll 8
            for (int k = c * 64; k < c * 64 + 64; k++) {
                float w = W[(size_t)k * DD];
                float4 a = *(const float4*)&shnT[k][0];
                acc0 += a.x * w; acc1 += a.y * w; acc2 += a.z * w; acc3 += a.w * w;
            }
            part[c][0][d] = acc0; part[c][1][d] = acc1;
            part[c][2][d] = acc2; part[c][3][d] = acc3;
        }
        __syncthreads();                                   // B3
        sh[c][d] = part[0][c][d] + part[1][c][d] + part[2][c][d] + part[3][c][d]
                 + bff[(size_t)l * DD + d] + sxp[c][d];
        // no barrier: next xp reads sh[c][d] written by this same thread;
        // next shnT write is separated from this layer's shnT reads by B3+B1.
    }
    __syncthreads();   // out-projection reads sh across rows

    // ---- out = h@Wout + b_out  (K split 4 ways) ----
    {
        int r = tid >> 8;          // row 0..3
        int sub = tid & 255;
        int e = sub & 63;
        int hf = sub >> 6;         // k-quarter 0..3
        float a = 0.0f;
        const float* W = Wout + e;
#pragma unroll 8
        for (int k = hf * 64; k < hf * 64 + 64; k++)
            a += sh[r][k] * W[(size_t)k * DOUT];
        part[hf][r][e] = a;
    }
    __syncthreads();
    if (tid < BM * DOUT) {
        int r = tid >> 6, e = tid & 63;
        out[(size_t)(n0 + r) * DOUT + e] =
            part[0][r][e] + part[1][r][e] + part[2][r][e] + part[3][r][e] + bout[e];
    }
}

// ---------------- host ----------------

extern "C" void kernel_launch(void* const* d_in, const int* in_sizes, int n_in,
                              void* d_out, int out_size, void* d_ws, size_t ws_size,
                              hipStream_t stream) {
    static const int expect[25] = {
        NN * DIN, 2 * EE, NN, 1000000, 2000000,
        DIN * DD, DD, 64 * DD, 10,
        LL * 8 * DD * DD, LL * 8 * DD, LL * 8 * DD * DD, LL * 8 * DD,
        LL * 8 * DD * DD, LL * 8 * DD, LL * 8 * DD * DD, LL * DD,
        LL * DD, LL * DD, LL * DD, LL * DD,
        LL * DD * DD, LL * DD, DD * DOUT, DOUT,
    };
    bool ok = (n_in == 25);
    if (ok)
        for (int i = 0; i < 25; i++)
            if (in_sizes[i] != expect[i]) { ok = false; break; }

    int* deg = (int*)d_ws;  // 8 KB
    if (!ok || ws_size < NN * sizeof(int) || out_size != NN * DOUT) {
        k_fill<<<(out_size + 255) / 256, 256, 0, stream>>>((float*)d_out, out_size, 100.0f);
        return;
    }

    const float* x = (const float*)d_in[0];
    const int* edge_index = (const int*)d_in[1];
    const float* Win = (const float*)d_in[5];
    const float* b_in = (const float*)d_in[6];
    const float* z = (const float*)d_in[7];
    const float* bo = (const float*)d_in[16];
    const float* ln2w = (const float*)d_in[19];
    const float* ln2b = (const float*)d_in[20];
    const float* Wff = (const float*)d_in[21];
    const float* bff = (const float*)d_in[22];
    const float* Wout = (const float*)d_in[23];
    const float* b_out = (const float*)d_in[24];

    hipMemsetAsync(deg, 0, NN * sizeof(int), stream);
    k_deg<<<EE / 256, 256, 0, stream>>>(edge_index, deg);
    k_mega<<<NN / BM, 1024, 0, stream>>>(x, deg, Win, b_in, z, bo, ln2w, ln2b,
                                         Wff, bff, Wout, b_out, (float*)d_out);
}